// Round 2
// baseline (261.978 us; speedup 1.0000x reference)
//
#include <hip/hip_runtime.h>
#include <math.h>

// LDSLoss: weighted MSE with label-distribution-smoothing weights.
//   mean = scaling * ( sum_{finite} w_i*sq_i + finite_max * sum_{inf} sq_i ) / (2N)
// One streaming pass; uniform-bin index + exact fixup replaces binary search;
// 4x float4-pair unroll for memory-level parallelism; last-block finalize.

#define BLOCK 256
#define GRID_CAP 2048   // 8 blocks/CU * 256 CU

// searchsorted(bins, x, 'right') - 1, clipped to [0, nb-1].
// Uniform-spacing guess + exact fixup against the true float32 edges.
__device__ __forceinline__ int find_bin(const float* __restrict__ sb, int nb,
                                        float x, float lo, float inv_step) {
    int idx = (int)floorf((x - lo) * inv_step);
    idx = idx < 0 ? 0 : (idx > nb - 1 ? nb - 1 : idx);
    while (idx > 0 && x < sb[idx]) --idx;                 // usually 0 iters
    while (idx < nb - 1 && x >= sb[idx + 1]) ++idx;       // usually 0-1 iters
    return idx;
}

__device__ __forceinline__ void process_pair(
    float4 in, float4 tg,
    const float* __restrict__ sb0, const float* __restrict__ sb1,
    const float* __restrict__ smoothed, int nb,
    float lo0, float inv0, float lo1, float inv1,
    double& a, double& b, float& m)
{
    // sample A
    float dA0 = in.x - tg.x, dA1 = in.y - tg.y;
    float sqA = dA0 * dA0 + dA1 * dA1;
    int iA0 = find_bin(sb0, nb, tg.x, lo0, inv0);
    int iA1 = find_bin(sb1, nb, tg.y, lo1, inv1);
    float sA = smoothed[iA0 * nb + iA1];
    // sample B
    float dB0 = in.z - tg.z, dB1 = in.w - tg.w;
    float sqB = dB0 * dB0 + dB1 * dB1;
    int iB0 = find_bin(sb0, nb, tg.z, lo0, inv0);
    int iB1 = find_bin(sb1, nb, tg.w, lo1, inv1);
    float sB = smoothed[iB0 * nb + iB1];

    float wA = 1.0f / sA;
    if (isinf(wA)) { b += (double)sqA; }
    else           { a += (double)(wA * sqA); m = fmaxf(m, wA); }
    float wB = 1.0f / sB;
    if (isinf(wB)) { b += (double)sqB; }
    else           { a += (double)(wB * sqB); m = fmaxf(m, wB); }
}

__global__ void __launch_bounds__(BLOCK)
lds_loss_fused(const float* __restrict__ input,
               const float* __restrict__ target,
               const float* __restrict__ smoothed,
               const float* __restrict__ bins0,
               const float* __restrict__ bins1,
               const float* __restrict__ scaling,
               int nb, long long n, long long nelem,
               double* __restrict__ accA,
               double* __restrict__ accB,
               unsigned int* __restrict__ accM,
               unsigned int* __restrict__ done_ctr,
               float* __restrict__ out)
{
    extern __shared__ float sbins[];           // [nb+1] bins0 | [nb+1] bins1
    float* sb0 = sbins;
    float* sb1 = sbins + (nb + 1);
    for (int i = threadIdx.x; i < nb + 1; i += BLOCK) {
        sb0[i] = bins0[i];
        sb1[i] = bins1[i];
    }
    __syncthreads();

    const float lo0 = sb0[0], inv0 = (float)nb / (sb0[nb] - sb0[0]);
    const float lo1 = sb1[0], inv1 = (float)nb / (sb1[nb] - sb1[0]);

    double a = 0.0, b = 0.0;
    float  m = 0.0f;                           // weights are > 0

    const long long npair = n >> 1;            // 2 samples (16 B) per pair
    const float4* in4 = (const float4*)input;
    const float4* tg4 = (const float4*)target;
    const long long stride = (long long)gridDim.x * BLOCK;

    long long p = (long long)blockIdx.x * BLOCK + threadIdx.x;
    // macro loop: 4 pairs (8 samples, 128 B) in flight per iteration
    for (; p + 3 * stride < npair; p += 4 * stride) {
        float4 i0 = in4[p];
        float4 i1 = in4[p + stride];
        float4 i2 = in4[p + 2 * stride];
        float4 i3 = in4[p + 3 * stride];
        float4 t0 = tg4[p];
        float4 t1 = tg4[p + stride];
        float4 t2 = tg4[p + 2 * stride];
        float4 t3 = tg4[p + 3 * stride];
        process_pair(i0, t0, sb0, sb1, smoothed, nb, lo0, inv0, lo1, inv1, a, b, m);
        process_pair(i1, t1, sb0, sb1, smoothed, nb, lo0, inv0, lo1, inv1, a, b, m);
        process_pair(i2, t2, sb0, sb1, smoothed, nb, lo0, inv0, lo1, inv1, a, b, m);
        process_pair(i3, t3, sb0, sb1, smoothed, nb, lo0, inv0, lo1, inv1, a, b, m);
    }
    for (; p < npair; p += stride) {
        process_pair(in4[p], tg4[p], sb0, sb1, smoothed, nb,
                     lo0, inv0, lo1, inv1, a, b, m);
    }

    // odd-N tail (not hit for N=8M)
    if ((n & 1) && blockIdx.x == 0 && threadIdx.x == 0) {
        long long i = n - 1;
        float t0 = target[2 * i], t1 = target[2 * i + 1];
        float d0 = input[2 * i] - t0, d1 = input[2 * i + 1] - t1;
        float sq = d0 * d0 + d1 * d1;
        int j0 = find_bin(sb0, nb, t0, lo0, inv0);
        int j1 = find_bin(sb1, nb, t1, lo1, inv1);
        float w = 1.0f / smoothed[j0 * nb + j1];
        if (isinf(w)) { b += (double)sq; }
        else          { a += (double)(w * sq); m = fmaxf(m, w); }
    }

    // wave-64 shuffle reduction
    #pragma unroll
    for (int off = 32; off > 0; off >>= 1) {
        a += __shfl_down(a, off, 64);
        b += __shfl_down(b, off, 64);
        m = fmaxf(m, __shfl_down(m, off, 64));
    }

    __shared__ double sA[BLOCK / 64], sB[BLOCK / 64];
    __shared__ float  sM[BLOCK / 64];
    int wave = threadIdx.x >> 6;
    int lane = threadIdx.x & 63;
    if (lane == 0) { sA[wave] = a; sB[wave] = b; sM[wave] = m; }
    __syncthreads();

    if (threadIdx.x == 0) {
        double ta = 0.0, tb = 0.0; float tm = 0.0f;
        #pragma unroll
        for (int w2 = 0; w2 < BLOCK / 64; ++w2) {
            ta += sA[w2]; tb += sB[w2]; tm = fmaxf(tm, sM[w2]);
        }
        atomicAdd(accA, ta);
        atomicAdd(accB, tb);
        atomicMax(accM, __float_as_uint(tm));   // positive floats: uint order == float
        __threadfence();
        unsigned int prev = atomicAdd(done_ctr, 1u);
        if (prev == gridDim.x - 1) {
            // last block: read back through atomic RMWs (coherent point)
            double A = atomicAdd(accA, 0.0);
            double B = atomicAdd(accB, 0.0);
            float  M = __uint_as_float(atomicMax(accM, 0u));
            double v = (double)(*scaling) * (A + (double)M * B) / (double)nelem;
            *out = (float)v;
        }
    }
}

extern "C" void kernel_launch(void* const* d_in, const int* in_sizes, int n_in,
                              void* d_out, int out_size, void* d_ws, size_t ws_size,
                              hipStream_t stream) {
    const float* input    = (const float*)d_in[0];
    const float* target   = (const float*)d_in[1];
    const float* smoothed = (const float*)d_in[2];
    const float* bins0    = (const float*)d_in[3];
    const float* bins1    = (const float*)d_in[4];
    const float* scaling  = (const float*)d_in[5];

    const long long nelem = in_sizes[0];       // N * 2
    const long long n     = nelem / 2;         // samples
    const int nb          = in_sizes[3] - 1;   // bins (edges - 1)

    double*       accA = (double*)d_ws;                    // @0
    double*       accB = accA + 1;                         // @8
    unsigned int* accM = (unsigned int*)(accB + 1);        // @16
    unsigned int* ctr  = accM + 1;                         // @20

    // d_ws is poisoned to 0xAA before every launch — zero the accumulators.
    hipMemsetAsync(d_ws, 0, 24, stream);

    long long blocks_needed = (n / 2 + BLOCK - 1) / BLOCK;
    int grid = (int)(blocks_needed < GRID_CAP ? blocks_needed : GRID_CAP);
    if (grid < 1) grid = 1;
    size_t shmem = (size_t)(nb + 1) * 2 * sizeof(float);

    lds_loss_fused<<<grid, BLOCK, shmem, stream>>>(
        input, target, smoothed, bins0, bins1, scaling,
        nb, n, nelem, accA, accB, accM, ctr, (float*)d_out);
}

// Round 3
// 200.109 us; speedup vs baseline: 1.3092x; 1.3092x over previous
//
#include <hip/hip_runtime.h>
#include <math.h>

// LDSLoss: weighted MSE with label-distribution-smoothing weights.
//   mean = scaling * ( sum_{finite} w_i*sq_i + finite_max * sum_{inf} sq_i ) / (2N)
//
// R3: the bottleneck (R1/R2 evidence) is the per-sample random gather into the
// 39 KB `smoothed` table — L1-thrashing divergent loads, MSHR-serialized.
// Fix: stage the ENTIRE table + bin edges in LDS; per-sample memory is then
// LDS-only (random over 32 banks ~= 2-way, near-free). Branchless bin fixup
// (no divergent loops). BLOCK=512, 40 KB shmem -> 4 blocks/CU = 32 waves/CU.

#define BLOCK 512
#define GRID_TARGET 1024   // 4 blocks/CU * 256 CU, exactly resident

// searchsorted(bins, x, 'right') - 1, clipped to [0, nb-1].
// Uniform-spacing guess + 2 branchless +-1 fixup steps against exact edges.
__device__ __forceinline__ int find_bin(const float* __restrict__ sb, int nb,
                                        float x, float lo, float inv_step) {
    int g = (int)floorf((x - lo) * inv_step);
    g = g < 0 ? 0 : (g > nb - 1 ? nb - 1 : g);
    #pragma unroll
    for (int s = 0; s < 2; ++s) {
        g -= (x < sb[g]) ? 1 : 0;          // move down if below this bin's left edge
        g = g < 0 ? 0 : g;
        g += (x >= sb[g + 1]) ? 1 : 0;     // move up if at/above right edge
        g = g > nb - 1 ? nb - 1 : g;
    }
    return g;
}

__device__ __forceinline__ void process_pair(
    float4 in, float4 tg,
    const float* __restrict__ sb0, const float* __restrict__ sb1,
    const float* __restrict__ stab, int nb,
    float lo0, float inv0, float lo1, float inv1,
    double& a, double& b, float& m)
{
    // sample A
    float dA0 = in.x - tg.x, dA1 = in.y - tg.y;
    float sqA = dA0 * dA0 + dA1 * dA1;
    int iA0 = find_bin(sb0, nb, tg.x, lo0, inv0);
    int iA1 = find_bin(sb1, nb, tg.y, lo1, inv1);
    float sA = stab[iA0 * nb + iA1];
    // sample B
    float dB0 = in.z - tg.z, dB1 = in.w - tg.w;
    float sqB = dB0 * dB0 + dB1 * dB1;
    int iB0 = find_bin(sb0, nb, tg.z, lo0, inv0);
    int iB1 = find_bin(sb1, nb, tg.w, lo1, inv1);
    float sB = stab[iB0 * nb + iB1];

    float wA = 1.0f / sA;
    if (isinf(wA)) { b += (double)sqA; }
    else           { a += (double)(wA * sqA); m = fmaxf(m, wA); }
    float wB = 1.0f / sB;
    if (isinf(wB)) { b += (double)sqB; }
    else           { a += (double)(wB * sqB); m = fmaxf(m, wB); }
}

__global__ void __launch_bounds__(BLOCK)
lds_loss_fused(const float* __restrict__ input,
               const float* __restrict__ target,
               const float* __restrict__ smoothed,
               const float* __restrict__ bins0,
               const float* __restrict__ bins1,
               const float* __restrict__ scaling,
               int nb, long long n, long long nelem,
               double* __restrict__ accA,
               double* __restrict__ accB,
               unsigned int* __restrict__ accM,
               unsigned int* __restrict__ done_ctr,
               float* __restrict__ out)
{
    extern __shared__ float smem[];
    float* sb0  = smem;                    // nb+1 edges, dim 0
    float* sb1  = smem + (nb + 1);         // nb+1 edges, dim 1
    float* stab = smem + 2 * (nb + 1);     // nb*nb smoothed table

    for (int i = threadIdx.x; i < nb * nb; i += BLOCK) stab[i] = smoothed[i];
    for (int i = threadIdx.x; i < nb + 1; i += BLOCK) {
        sb0[i] = bins0[i];
        sb1[i] = bins1[i];
    }
    __syncthreads();

    const float lo0 = sb0[0], inv0 = (float)nb / (sb0[nb] - sb0[0]);
    const float lo1 = sb1[0], inv1 = (float)nb / (sb1[nb] - sb1[0]);

    double a = 0.0, b = 0.0;
    float  m = 0.0f;                       // weights are > 0

    const long long npair = n >> 1;        // 2 samples (16 B) per pair
    const float4* in4 = (const float4*)input;
    const float4* tg4 = (const float4*)target;
    const long long stride = (long long)gridDim.x * BLOCK;

    long long p = (long long)blockIdx.x * BLOCK + threadIdx.x;
    // macro loop: 4 pairs (8 samples, 128 B) in flight per iteration
    for (; p + 3 * stride < npair; p += 4 * stride) {
        float4 i0 = in4[p];
        float4 i1 = in4[p + stride];
        float4 i2 = in4[p + 2 * stride];
        float4 i3 = in4[p + 3 * stride];
        float4 t0 = tg4[p];
        float4 t1 = tg4[p + stride];
        float4 t2 = tg4[p + 2 * stride];
        float4 t3 = tg4[p + 3 * stride];
        process_pair(i0, t0, sb0, sb1, stab, nb, lo0, inv0, lo1, inv1, a, b, m);
        process_pair(i1, t1, sb0, sb1, stab, nb, lo0, inv0, lo1, inv1, a, b, m);
        process_pair(i2, t2, sb0, sb1, stab, nb, lo0, inv0, lo1, inv1, a, b, m);
        process_pair(i3, t3, sb0, sb1, stab, nb, lo0, inv0, lo1, inv1, a, b, m);
    }
    for (; p < npair; p += stride) {
        process_pair(in4[p], tg4[p], sb0, sb1, stab, nb,
                     lo0, inv0, lo1, inv1, a, b, m);
    }

    // odd-N tail (not hit for N=8M)
    if ((n & 1) && blockIdx.x == 0 && threadIdx.x == 0) {
        long long i = n - 1;
        float t0 = target[2 * i], t1 = target[2 * i + 1];
        float d0 = input[2 * i] - t0, d1 = input[2 * i + 1] - t1;
        float sq = d0 * d0 + d1 * d1;
        int j0 = find_bin(sb0, nb, t0, lo0, inv0);
        int j1 = find_bin(sb1, nb, t1, lo1, inv1);
        float w = 1.0f / stab[j0 * nb + j1];
        if (isinf(w)) { b += (double)sq; }
        else          { a += (double)(w * sq); m = fmaxf(m, w); }
    }

    // wave-64 shuffle reduction
    #pragma unroll
    for (int off = 32; off > 0; off >>= 1) {
        a += __shfl_down(a, off, 64);
        b += __shfl_down(b, off, 64);
        m = fmaxf(m, __shfl_down(m, off, 64));
    }

    __shared__ double sA[BLOCK / 64], sB[BLOCK / 64];
    __shared__ float  sM[BLOCK / 64];
    int wave = threadIdx.x >> 6;
    int lane = threadIdx.x & 63;
    if (lane == 0) { sA[wave] = a; sB[wave] = b; sM[wave] = m; }
    __syncthreads();

    if (threadIdx.x == 0) {
        double ta = 0.0, tb = 0.0; float tm = 0.0f;
        #pragma unroll
        for (int w2 = 0; w2 < BLOCK / 64; ++w2) {
            ta += sA[w2]; tb += sB[w2]; tm = fmaxf(tm, sM[w2]);
        }
        atomicAdd(accA, ta);
        atomicAdd(accB, tb);
        atomicMax(accM, __float_as_uint(tm));   // positive floats: uint order == float
        __threadfence();
        unsigned int prev = atomicAdd(done_ctr, 1u);
        if (prev == gridDim.x - 1) {
            // last block: read back through atomic RMWs (coherent point)
            double A = atomicAdd(accA, 0.0);
            double B = atomicAdd(accB, 0.0);
            float  M = __uint_as_float(atomicMax(accM, 0u));
            double v = (double)(*scaling) * (A + (double)M * B) / (double)nelem;
            *out = (float)v;
        }
    }
}

extern "C" void kernel_launch(void* const* d_in, const int* in_sizes, int n_in,
                              void* d_out, int out_size, void* d_ws, size_t ws_size,
                              hipStream_t stream) {
    const float* input    = (const float*)d_in[0];
    const float* target   = (const float*)d_in[1];
    const float* smoothed = (const float*)d_in[2];
    const float* bins0    = (const float*)d_in[3];
    const float* bins1    = (const float*)d_in[4];
    const float* scaling  = (const float*)d_in[5];

    const long long nelem = in_sizes[0];       // N * 2
    const long long n     = nelem / 2;         // samples
    const int nb          = in_sizes[3] - 1;   // bins (edges - 1)

    double*       accA = (double*)d_ws;                    // @0
    double*       accB = accA + 1;                         // @8
    unsigned int* accM = (unsigned int*)(accB + 1);        // @16
    unsigned int* ctr  = accM + 1;                         // @20

    // d_ws is poisoned to 0xAA before every launch — zero the accumulators.
    hipMemsetAsync(d_ws, 0, 24, stream);

    long long blocks_needed = (n / 2 + BLOCK - 1) / BLOCK;
    int grid = (int)(blocks_needed < GRID_TARGET ? blocks_needed : GRID_TARGET);
    if (grid < 1) grid = 1;
    // shmem: 2*(nb+1) edges + nb*nb table. nb=99 -> 40,004 B (4 blocks/CU).
    size_t shmem = ((size_t)2 * (nb + 1) + (size_t)nb * nb) * sizeof(float);

    lds_loss_fused<<<grid, BLOCK, shmem, stream>>>(
        input, target, smoothed, bins0, bins1, scaling,
        nb, n, nelem, accA, accB, accM, ctr, (float*)d_out);
}